// Round 10
// baseline (153.613 us; speedup 1.0000x reference)
//
#include <hip/hip_runtime.h>
#include <hip/hip_bf16.h>
#include <math.h>

#define T_STEPS 65536
#define DDIM 256
#define RDIM 32
#define MDIM 52
#define CHUNK 64
#define NCH (T_STEPS / CHUNK)   // 1024 chunks
#define SCH 16                  // chunks per superchunk
#define NSC (NCH / SCH)         // 64 superchunks

typedef short short8 __attribute__((ext_vector_type(8)));   // 8 bf16 (4 VGPRs)
typedef float f32x4  __attribute__((ext_vector_type(4)));   // MFMA acc

union bf8pack { short8 v; __hip_bfloat16 h[8]; };

// ---------------------------------------------------------------------------
// K0: pack W = [Wk;Wv;Wq] (96x256) into MFMA B-frag order (bf16), and
// Wo (52x32, zero-padded to 64 rows) into WoFrag.
// frag[(tile*nK + kb)*64 + lane][j] = M[16*tile + (lane&15)][kb*32 + (lane>>4)*8 + j]
// ---------------------------------------------------------------------------
__global__ __launch_bounds__(256) void prepB_kernel(
    const float* __restrict__ Wk, const float* __restrict__ Wv,
    const float* __restrict__ Wq, const float* __restrict__ Wo,
    __hip_bfloat16* __restrict__ Bfrag, __hip_bfloat16* __restrict__ WoFrag)
{
    const int idx = blockIdx.x * 256 + threadIdx.x;
    if (idx < 6 * 8 * 64) {
        const int lane = idx & 63;
        const int kb   = (idx >> 6) & 7;
        const int c    = idx >> 9;
        const int row  = 16 * c + (lane & 15);            // 0..95
        const int k0   = kb * 32 + (lane >> 4) * 8;       // 0..248
        const float* src = (row < 32) ? (Wk + (size_t)row * DDIM)
                         : (row < 64) ? (Wv + (size_t)(row - 32) * DDIM)
                                      : (Wq + (size_t)(row - 64) * DDIM);
        bf8pack p;
#pragma unroll
        for (int j = 0; j < 8; j++) p.h[j] = __float2bfloat16(src[k0 + j]);
        *(short8*)(Bfrag + (size_t)idx * 8) = p.v;
    } else if (idx < 6 * 8 * 64 + 4 * 64) {
        const int i2   = idx - 6 * 8 * 64;                // 0..255
        const int lane = i2 & 63;
        const int c    = i2 >> 6;                         // n-tile 0..3
        const int mm   = 16 * c + (lane & 15);            // 0..63 (pad >=52)
        const int k0   = (lane >> 4) * 8;                 // 0..24
        bf8pack p;
#pragma unroll
        for (int j = 0; j < 8; j++)
            p.h[j] = __float2bfloat16(mm < MDIM ? Wo[(size_t)mm * 32 + k0 + j] : 0.f);
        *(short8*)(WoFrag + (size_t)i2 * 8) = p.v;
    }
}

// ---------------------------------------------------------------------------
// K1: MFMA projections + phase A + intra-chunk attention, all in one block.
// Outputs: Qtil (bf16 plane, b*q), Fin (intra-chunk fast-out, bf16 stored in
// MFMA C-layout [ch][wave][lane][8] for direct phaseC consumption),
// S = P*k̃^T v (fp32), P.
// ---------------------------------------------------------------------------
__global__ __launch_bounds__(256) void projA_kernel(
    const float* __restrict__ X,
    const float* __restrict__ lr, const float* __restrict__ decay,
    const float* __restrict__ bk, const float* __restrict__ bv,
    const float* __restrict__ bq,
    const __hip_bfloat16* __restrict__ Bfrag,
    __hip_bfloat16* __restrict__ Qtil, __hip_bfloat16* __restrict__ Fin,
    float* __restrict__ Schunk, float* __restrict__ Pchunk)
{
    __shared__ __hip_bfloat16 kR[CHUNK][40];  // k̃ rows (scores B-frag)
    __shared__ __hip_bfloat16 qR[CHUNK][40];  // q̃ rows (A-frag + plane copy)
    __shared__ __hip_bfloat16 kT[32][72];     // k̃^T (S-MFMA A-frag)
    __shared__ __hip_bfloat16 vT[32][72];     // v^T  (S-MFMA + PV B-frag)
    __shared__ __hip_bfloat16 scb[CHUNK][72]; // masked scores
    __shared__ float bbS[CHUNK], llS[CHUNK], biasS[96];

    const int tid  = threadIdx.x;
    const int wv   = tid >> 6;
    const int lane = tid & 63;
    const int l15  = lane & 15;
    const int q4   = lane >> 4;
    const int ch   = blockIdx.x;
    const int t0   = ch * CHUNK;

    if (wv == 0) {                      // decay cumprod via shfl prefix
        float b = 1.f - decay[t0 + lane];
        float l = lr[t0 + lane];
#pragma unroll
        for (int d = 1; d < 64; d <<= 1) {
            float o = __shfl_up(b, d, 64);
            if (lane >= d) b *= o;
        }
        bbS[lane] = b; llS[lane] = l;
    }
    if (tid < 96)
        biasS[tid] = (tid < 32) ? bk[tid] : (tid < 64) ? bv[tid - 32] : bq[tid - 64];

    // MFMA GEMM: C[64x96] = X_tile[64x256] * W^T  — all 16 X loads hoisted
    const float* xrow = X + (size_t)(t0 + 16 * wv + l15) * DDIM + q4 * 8;
    float4 xa[16];
#pragma unroll
    for (int kb = 0; kb < 8; kb++) {
        xa[2 * kb]     = *(const float4*)(xrow + kb * 32);
        xa[2 * kb + 1] = *(const float4*)(xrow + kb * 32 + 4);
    }
    f32x4 acc[6];
#pragma unroll
    for (int c = 0; c < 6; c++) acc[c] = (f32x4){0.f, 0.f, 0.f, 0.f};
#pragma unroll
    for (int kb = 0; kb < 8; kb++) {
        const float4 a0 = xa[2 * kb], a1 = xa[2 * kb + 1];
        bf8pack ap;
        ap.h[0] = __float2bfloat16(a0.x); ap.h[1] = __float2bfloat16(a0.y);
        ap.h[2] = __float2bfloat16(a0.z); ap.h[3] = __float2bfloat16(a0.w);
        ap.h[4] = __float2bfloat16(a1.x); ap.h[5] = __float2bfloat16(a1.y);
        ap.h[6] = __float2bfloat16(a1.z); ap.h[7] = __float2bfloat16(a1.w);
#pragma unroll
        for (int c = 0; c < 6; c++) {
            short8 bf = *(const short8*)(Bfrag + ((size_t)(c * 8 + kb) * 64 + lane) * 8);
            acc[c] = __builtin_amdgcn_mfma_f32_16x16x32_bf16(ap.v, bf, acc[c], 0, 0, 0);
        }
    }
    __syncthreads();                    // bb/ll/bias ready
    const float P = bbS[63];

    // scatter accumulators into bf16 LDS tiles (with per-row scaling)
#pragma unroll
    for (int c = 0; c < 6; c++) {
        const int colg = 16 * c + l15;
        const float bias = biasS[colg];
#pragma unroll
        for (int r = 0; r < 4; r++) {
            const int sloc = 16 * wv + 4 * q4 + r;
            const float val = acc[c][r] + bias;
            if (c < 2) {
                __hip_bfloat16 h = __float2bfloat16(val * (llS[sloc] / bbS[sloc]));
                kR[sloc][colg] = h;
                kT[colg][sloc] = h;
            } else if (c < 4) {
                vT[colg - 32][sloc] = __float2bfloat16(val);
            } else {
                qR[sloc][colg - 64] = __float2bfloat16(val * bbS[sloc]);
            }
        }
    }
    __syncthreads();

    // coalesced Qtil plane write
    {
        const int s = tid >> 2, g = (tid & 3) * 8;
        *(short8*)(Qtil + (size_t)(t0 + s) * 32 + g) = *(const short8*)(&qR[s][g]);
    }

    // S[a][b] = P * sum_s kT[a][s] vT[b][s]  (one MFMA quadrant per wave)
    {
        const int am = wv & 1, bn = wv >> 1;
        f32x4 sacc = (f32x4){0.f, 0.f, 0.f, 0.f};
#pragma unroll
        for (int k2 = 0; k2 < 2; k2++) {
            short8 aF = *(const short8*)(&kT[16 * am + l15][k2 * 32 + q4 * 8]);
            short8 bF = *(const short8*)(&vT[16 * bn + l15][k2 * 32 + q4 * 8]);
            sacc = __builtin_amdgcn_mfma_f32_16x16x32_bf16(aF, bF, sacc, 0, 0, 0);
        }
        float* Sout = Schunk + (size_t)ch * 1024;
#pragma unroll
        for (int rr = 0; rr < 4; rr++)
            Sout[(16 * am + 4 * q4 + rr) * 32 + (16 * bn + l15)] = P * sacc[rr];
    }
    if (tid == 0) Pchunk[ch] = P;

    // scores: Q̃ K̃^T (4 MFMAs/wave), mask s<=t, bf16 -> scb
    const short8 aq = *(const short8*)(&qR[16 * wv + l15][q4 * 8]);
    f32x4 sc4[4];
#pragma unroll
    for (int sn = 0; sn < 4; sn++) {
        short8 bk8 = *(const short8*)(&kR[16 * sn + l15][q4 * 8]);
        sc4[sn] = __builtin_amdgcn_mfma_f32_16x16x32_bf16(
            aq, bk8, (f32x4){0.f, 0.f, 0.f, 0.f}, 0, 0, 0);
    }
#pragma unroll
    for (int sn = 0; sn < 4; sn++) {
#pragma unroll
        for (int rr = 0; rr < 4; rr++) {
            const int t = 16 * wv + 4 * q4 + rr;
            const int s = 16 * sn + l15;
            scb[t][s] = __float2bfloat16((s <= t) ? sc4[sn][rr] : 0.f);
        }
    }
    __syncthreads();   // scb ready

    // Fin = Sc·V : 64x32, K=64 (4 MFMAs/wave), stored in C-layout bf16
    f32x4 fin[2] = {(f32x4){0.f,0.f,0.f,0.f}, (f32x4){0.f,0.f,0.f,0.f}};
#pragma unroll
    for (int kb = 0; kb < 2; kb++) {
        short8 ap8 = *(const short8*)(&scb[16 * wv + l15][kb * 32 + q4 * 8]);
#pragma unroll
        for (int rn = 0; rn < 2; rn++) {
            short8 bv8 = *(const short8*)(&vT[16 * rn + l15][kb * 32 + q4 * 8]);
            fin[rn] = __builtin_amdgcn_mfma_f32_16x16x32_bf16(ap8, bv8, fin[rn], 0, 0, 0);
        }
    }
    {
        bf8pack pf;
#pragma unroll
        for (int rr = 0; rr < 4; rr++) {
            pf.h[rr]     = __float2bfloat16(fin[0][rr]);
            pf.h[4 + rr] = __float2bfloat16(fin[1][rr]);
        }
        *(short8*)(Fin + ((size_t)(ch * 4 + wv) * 64 + lane) * 8) = pf.v;
    }
}

// ---------------------------------------------------------------------------
// K2 (B1): local scan inside each superchunk (16 seq iters, 64 blocks).
// ---------------------------------------------------------------------------
__global__ __launch_bounds__(256) void phaseB1_kernel(
    const float* __restrict__ Schunk, const float* __restrict__ Pchunk,
    float* __restrict__ Wlocal, float* __restrict__ AP,
    float* __restrict__ Wtotal, float* __restrict__ Atot)
{
    const int sc  = blockIdx.x;
    const int tid = threadIdx.x;
    const int e4  = tid * 4;
    float4 w = make_float4(0.f, 0.f, 0.f, 0.f);
    float  a = 1.f;
#pragma unroll 4
    for (int c = 0; c < SCH; c++) {
        const int ch = sc * SCH + c;
        const float p = Pchunk[ch];
        if (tid == 0) AP[ch] = a;
        *(float4*)(Wlocal + (size_t)ch * 1024 + e4) = w;
        float4 s = *(const float4*)(Schunk + (size_t)ch * 1024 + e4);
        w.x = p * w.x + s.x;  w.y = p * w.y + s.y;
        w.z = p * w.z + s.z;  w.w = p * w.w + s.w;
        a *= p;
    }
    *(float4*)(Wtotal + (size_t)sc * 1024 + e4) = w;
    if (tid == 0) Atot[sc] = a;
}

// ---------------------------------------------------------------------------
// K3 (phase C): inline-B2 + carried-state term + epilogue.
//   Wsuper scan (<=63 L2-hot iters) -> Wst = AP*Wsuper + Wlocal
//   fast = Fin (C-layout bf16, direct C-operand init) + Q̃·Wst  [2 MFMAs]
//   out  = 1 + tanh(fast Wo^T + bo)                             [4 MFMAs + exp]
// ---------------------------------------------------------------------------
__global__ __launch_bounds__(256) void phaseC_kernel(
    const __hip_bfloat16* __restrict__ Qtil,
    const __hip_bfloat16* __restrict__ Fin,
    const float* __restrict__ Wlocal, const float* __restrict__ AP,
    const float* __restrict__ Wtotal, const float* __restrict__ Atot,
    const __hip_bfloat16* __restrict__ WoFrag, const float* __restrict__ bo,
    float* __restrict__ out)
{
    __shared__ __hip_bfloat16 WstT[32][40];     // Wst^T, bf16
    __shared__ __hip_bfloat16 fastB[CHUNK][40]; // fast_out, bf16 (A-frag for epi)
    __shared__ float bosS[MDIM];

    const int tid  = threadIdx.x;
    const int wv   = tid >> 6;
    const int lane = tid & 63;
    const int l15  = lane & 15;
    const int q4   = lane >> 4;
    const int ch   = blockIdx.x;
    const int t0   = ch * CHUNK;
    const int scid = ch / SCH;

    // inline B2: Wsuper[scid] for this block, then Wst^T staging (bf16)
    {
        const int e4 = tid * 4;
        float4 w = make_float4(0.f, 0.f, 0.f, 0.f);
        for (int s = 0; s < scid; s++) {
            const float p = Atot[s];
            float4 t = *(const float4*)(Wtotal + (size_t)s * 1024 + e4);
            w.x = p * w.x + t.x;  w.y = p * w.y + t.y;
            w.z = p * w.z + t.z;  w.w = p * w.w + t.w;
        }
        const float ap = AP[ch];
        float4 wl = *(const float4*)(Wlocal + (size_t)ch * 1024 + e4);
        const int a  = tid >> 3;
        const int r0 = (tid & 7) * 4;
        WstT[r0 + 0][a] = __float2bfloat16(ap * w.x + wl.x);
        WstT[r0 + 1][a] = __float2bfloat16(ap * w.y + wl.y);
        WstT[r0 + 2][a] = __float2bfloat16(ap * w.z + wl.z);
        WstT[r0 + 3][a] = __float2bfloat16(ap * w.w + wl.w);
    }
    if (tid < MDIM) bosS[tid] = bo[tid];

    // A-fragment: q̃ rows of this wave's t-tile
    const short8 aq = *(const short8*)(Qtil + (size_t)(t0 + 16 * wv + l15) * 32 + q4 * 8);
    // Fin (C-layout) -> C-operand init
    bf8pack pf;
    pf.v = *(const short8*)(Fin + ((size_t)(ch * 4 + wv) * 64 + lane) * 8);
    f32x4 fa[2];
#pragma unroll
    for (int rr = 0; rr < 4; rr++) {
        fa[0][rr] = __bfloat162float(pf.h[rr]);
        fa[1][rr] = __bfloat162float(pf.h[4 + rr]);
    }
    __syncthreads();   // WstT ready

    // fast = Fin + Q̃·Wst
#pragma unroll
    for (int rn = 0; rn < 2; rn++) {
        short8 bw8 = *(const short8*)(&WstT[16 * rn + l15][q4 * 8]);
        fa[rn] = __builtin_amdgcn_mfma_f32_16x16x32_bf16(aq, bw8, fa[rn], 0, 0, 0);
    }
    // fast -> LDS (bf16, A-frag layout source)
#pragma unroll
    for (int rn = 0; rn < 2; rn++)
#pragma unroll
        for (int rr = 0; rr < 4; rr++)
            fastB[16 * wv + 4 * q4 + rr][16 * rn + l15] = __float2bfloat16(fa[rn][rr]);
    __syncthreads();

    // epilogue: out = 1 + tanh(fast @ Wo^T + bo), via 4 MFMAs/wave (K=32)
    {
        const short8 aF = *(const short8*)(&fastB[16 * wv + l15][q4 * 8]);
#pragma unroll
        for (int c = 0; c < 4; c++) {
            short8 bF = *(const short8*)(WoFrag + ((size_t)(c * 64) + lane) * 8);
            f32x4 oc = __builtin_amdgcn_mfma_f32_16x16x32_bf16(
                aF, bF, (f32x4){0.f, 0.f, 0.f, 0.f}, 0, 0, 0);
            const int mm = 16 * c + l15;
            if (mm < MDIM) {
                const float bb = bosS[mm];
#pragma unroll
                for (int rr = 0; rr < 4; rr++) {
                    const int t = 16 * wv + 4 * q4 + rr;
                    out[(size_t)(t0 + t) * MDIM + mm] =
                        2.0f / (1.0f + __expf(-2.0f * (oc[rr] + bb)));
                }
            }
        }
    }
}

// ---------------------------------------------------------------------------
extern "C" void kernel_launch(void* const* d_in, const int* in_sizes, int n_in,
                              void* d_out, int out_size, void* d_ws, size_t ws_size,
                              hipStream_t stream) {
    (void)in_sizes; (void)n_in; (void)out_size; (void)ws_size;
    const float* X   = (const float*)d_in[0];
    const float* lr  = (const float*)d_in[1];
    const float* dec = (const float*)d_in[2];
    const float* Wk  = (const float*)d_in[3];
    const float* bk  = (const float*)d_in[4];
    const float* Wv  = (const float*)d_in[5];
    const float* bv  = (const float*)d_in[6];
    const float* Wq  = (const float*)d_in[7];
    const float* bq  = (const float*)d_in[8];
    const float* Wo  = (const float*)d_in[9];
    const float* bo  = (const float*)d_in[10];
    float* out = (float*)d_out;

    // workspace (floats unless noted):
    // S[NCH*1024] | P[NCH] | AP[NCH] | Wlocal[NCH*1024] | Wtotal[NSC*1024]
    // | Atot[NSC] | Qtil(bf16 T*32) | Fin(bf16 T*32) | Bfrag | WoFrag
    float* ws    = (float*)d_ws;
    float* S     = ws;
    float* P     = S + (size_t)NCH * 1024;
    float* APb   = P + NCH;
    float* Wloc  = APb + NCH;
    float* Wtot  = Wloc + (size_t)NCH * 1024;
    float* Atot  = Wtot + (size_t)NSC * 1024;
    __hip_bfloat16* Qtil   = (__hip_bfloat16*)(Atot + NSC);
    __hip_bfloat16* Fin    = Qtil + (size_t)T_STEPS * 32;
    __hip_bfloat16* Bfrag  = Fin + (size_t)T_STEPS * 32;
    __hip_bfloat16* WoFrag = Bfrag + (size_t)96 * 256;

    prepB_kernel<<<13, 256, 0, stream>>>(Wk, Wv, Wq, Wo, Bfrag, WoFrag);
    projA_kernel<<<NCH, 256, 0, stream>>>(X, lr, dec, bk, bv, bq, Bfrag,
                                          Qtil, Fin, S, P);
    phaseB1_kernel<<<NSC, 256, 0, stream>>>(S, P, Wloc, APb, Wtot, Atot);
    phaseC_kernel<<<NCH, 256, 0, stream>>>(Qtil, Fin, Wloc, APb,
                                           Wtot, Atot, WoFrag, bo, out);
}

// Round 11
// 149.325 us; speedup vs baseline: 1.0287x; 1.0287x over previous
//
#include <hip/hip_runtime.h>
#include <hip/hip_bf16.h>
#include <math.h>

#define T_STEPS 65536
#define DDIM 256
#define RDIM 32
#define MDIM 52
#define CHUNK 64
#define NCH (T_STEPS / CHUNK)   // 1024 chunks
#define SCH 16                  // chunks per superchunk
#define NSC (NCH / SCH)         // 64 superchunks

typedef short short8 __attribute__((ext_vector_type(8)));   // 8 bf16 (4 VGPRs)
typedef float f32x4  __attribute__((ext_vector_type(4)));   // MFMA acc

union bf8pack { short8 v; __hip_bfloat16 h[8]; };

// ---------------------------------------------------------------------------
// K0: pack W = [Wk;Wv;Wq] (96x256) into MFMA B-frag order (bf16), and
// Wo (52x32, zero-padded to 64 rows) into WoFrag.
// frag[(tile*nK + kb)*64 + lane][j] = M[16*tile + (lane&15)][kb*32 + (lane>>4)*8 + j]
// ---------------------------------------------------------------------------
__global__ __launch_bounds__(256) void prepB_kernel(
    const float* __restrict__ Wk, const float* __restrict__ Wv,
    const float* __restrict__ Wq, const float* __restrict__ Wo,
    __hip_bfloat16* __restrict__ Bfrag, __hip_bfloat16* __restrict__ WoFrag)
{
    const int idx = blockIdx.x * 256 + threadIdx.x;
    if (idx < 6 * 8 * 64) {
        const int lane = idx & 63;
        const int kb   = (idx >> 6) & 7;
        const int c    = idx >> 9;
        const int row  = 16 * c + (lane & 15);            // 0..95
        const int k0   = kb * 32 + (lane >> 4) * 8;       // 0..248
        const float* src = (row < 32) ? (Wk + (size_t)row * DDIM)
                         : (row < 64) ? (Wv + (size_t)(row - 32) * DDIM)
                                      : (Wq + (size_t)(row - 64) * DDIM);
        bf8pack p;
#pragma unroll
        for (int j = 0; j < 8; j++) p.h[j] = __float2bfloat16(src[k0 + j]);
        *(short8*)(Bfrag + (size_t)idx * 8) = p.v;
    } else if (idx < 6 * 8 * 64 + 4 * 64) {
        const int i2   = idx - 6 * 8 * 64;                // 0..255
        const int lane = i2 & 63;
        const int c    = i2 >> 6;                         // n-tile 0..3
        const int mm   = 16 * c + (lane & 15);            // 0..63 (pad >=52)
        const int k0   = (lane >> 4) * 8;                 // 0..24
        bf8pack p;
#pragma unroll
        for (int j = 0; j < 8; j++)
            p.h[j] = __float2bfloat16(mm < MDIM ? Wo[(size_t)mm * 32 + k0 + j] : 0.f);
        *(short8*)(WoFrag + (size_t)i2 * 8) = p.v;
    }
}

// ---------------------------------------------------------------------------
// K1: MFMA projections + phase A + intra-chunk attention. 2 barriers only:
// decay cumprod is computed redundantly per-wave (shfl, no LDS), biases read
// per-lane from L1-hot global.
// Outputs: Qtil (bf16 plane), Fin (bf16, MFMA C-layout), S = P*k̃^T v, P.
// ---------------------------------------------------------------------------
__global__ __launch_bounds__(256) void projA_kernel(
    const float* __restrict__ X,
    const float* __restrict__ lr, const float* __restrict__ decay,
    const float* __restrict__ bk, const float* __restrict__ bv,
    const float* __restrict__ bq,
    const __hip_bfloat16* __restrict__ Bfrag,
    __hip_bfloat16* __restrict__ Qtil, __hip_bfloat16* __restrict__ Fin,
    float* __restrict__ Schunk, float* __restrict__ Pchunk)
{
    __shared__ __hip_bfloat16 kR[CHUNK][40];  // k̃ rows (scores B-frag)
    __shared__ __hip_bfloat16 qR[CHUNK][40];  // q̃ rows (A-frag + plane copy)
    __shared__ __hip_bfloat16 kT[32][72];     // k̃^T (S-MFMA A-frag)
    __shared__ __hip_bfloat16 vT[32][72];     // v^T  (S-MFMA + PV B-frag)
    __shared__ __hip_bfloat16 scb[CHUNK][72]; // masked scores

    const int tid  = threadIdx.x;
    const int wv   = tid >> 6;
    const int lane = tid & 63;
    const int l15  = lane & 15;
    const int q4   = lane >> 4;
    const int ch   = blockIdx.x;
    const int t0   = ch * CHUNK;

    // redundant per-wave decay cumprod (overlaps X-load latency; no LDS/barrier)
    float bcum = 1.f - decay[t0 + lane];
    const float lcum = lr[t0 + lane];
#pragma unroll
    for (int d = 1; d < 64; d <<= 1) {
        float o = __shfl_up(bcum, d, 64);
        if (lane >= d) bcum *= o;
    }
    const float P = __shfl(bcum, 63, 64);

    // MFMA GEMM: C[64x96] = X_tile[64x256] * W^T  — all 16 X loads hoisted
    const float* xrow = X + (size_t)(t0 + 16 * wv + l15) * DDIM + q4 * 8;
    float4 xa[16];
#pragma unroll
    for (int kb = 0; kb < 8; kb++) {
        xa[2 * kb]     = *(const float4*)(xrow + kb * 32);
        xa[2 * kb + 1] = *(const float4*)(xrow + kb * 32 + 4);
    }
    f32x4 acc[6];
#pragma unroll
    for (int c = 0; c < 6; c++) acc[c] = (f32x4){0.f, 0.f, 0.f, 0.f};
#pragma unroll
    for (int kb = 0; kb < 8; kb++) {
        const float4 a0 = xa[2 * kb], a1 = xa[2 * kb + 1];
        bf8pack ap;
        ap.h[0] = __float2bfloat16(a0.x); ap.h[1] = __float2bfloat16(a0.y);
        ap.h[2] = __float2bfloat16(a0.z); ap.h[3] = __float2bfloat16(a0.w);
        ap.h[4] = __float2bfloat16(a1.x); ap.h[5] = __float2bfloat16(a1.y);
        ap.h[6] = __float2bfloat16(a1.z); ap.h[7] = __float2bfloat16(a1.w);
#pragma unroll
        for (int c = 0; c < 6; c++) {
            short8 bf = *(const short8*)(Bfrag + ((size_t)(c * 8 + kb) * 64 + lane) * 8);
            acc[c] = __builtin_amdgcn_mfma_f32_16x16x32_bf16(ap.v, bf, acc[c], 0, 0, 0);
        }
    }

    // per-row scales for this lane's 4 accumulator rows (sloc = 16wv+4q4+r)
    float bbr[4], llr[4];
#pragma unroll
    for (int r = 0; r < 4; r++) {
        const int sloc = 16 * wv + 4 * q4 + r;
        bbr[r] = __shfl(bcum, sloc, 64);
        llr[r] = __shfl(lcum, sloc, 64);
    }

    // scatter accumulators into bf16 LDS tiles (bias from L1-hot global)
#pragma unroll
    for (int c = 0; c < 6; c++) {
        const int colg = 16 * c + l15;
        const float bias = (colg < 32) ? bk[colg]
                         : (colg < 64) ? bv[colg - 32] : bq[colg - 64];
#pragma unroll
        for (int r = 0; r < 4; r++) {
            const int sloc = 16 * wv + 4 * q4 + r;
            const float val = acc[c][r] + bias;
            if (c < 2) {
                __hip_bfloat16 h = __float2bfloat16(val * (llr[r] / bbr[r]));
                kR[sloc][colg] = h;
                kT[colg][sloc] = h;
            } else if (c < 4) {
                vT[colg - 32][sloc] = __float2bfloat16(val);
            } else {
                qR[sloc][colg - 64] = __float2bfloat16(val * bbr[r]);
            }
        }
    }
    __syncthreads();                    // tiles ready

    // coalesced Qtil plane write
    {
        const int s = tid >> 2, g = (tid & 3) * 8;
        *(short8*)(Qtil + (size_t)(t0 + s) * 32 + g) = *(const short8*)(&qR[s][g]);
    }

    // S[a][b] = P * sum_s kT[a][s] vT[b][s]  (one MFMA quadrant per wave)
    {
        const int am = wv & 1, bn = wv >> 1;
        f32x4 sacc = (f32x4){0.f, 0.f, 0.f, 0.f};
#pragma unroll
        for (int k2 = 0; k2 < 2; k2++) {
            short8 aF = *(const short8*)(&kT[16 * am + l15][k2 * 32 + q4 * 8]);
            short8 bF = *(const short8*)(&vT[16 * bn + l15][k2 * 32 + q4 * 8]);
            sacc = __builtin_amdgcn_mfma_f32_16x16x32_bf16(aF, bF, sacc, 0, 0, 0);
        }
        float* Sout = Schunk + (size_t)ch * 1024;
#pragma unroll
        for (int rr = 0; rr < 4; rr++)
            Sout[(16 * am + 4 * q4 + rr) * 32 + (16 * bn + l15)] = P * sacc[rr];
    }
    if (tid == 0) Pchunk[ch] = P;

    // scores: Q̃ K̃^T (4 MFMAs/wave), mask s<=t, bf16 -> scb
    const short8 aq = *(const short8*)(&qR[16 * wv + l15][q4 * 8]);
    f32x4 sc4[4];
#pragma unroll
    for (int sn = 0; sn < 4; sn++) {
        short8 bk8 = *(const short8*)(&kR[16 * sn + l15][q4 * 8]);
        sc4[sn] = __builtin_amdgcn_mfma_f32_16x16x32_bf16(
            aq, bk8, (f32x4){0.f, 0.f, 0.f, 0.f}, 0, 0, 0);
    }
#pragma unroll
    for (int sn = 0; sn < 4; sn++) {
#pragma unroll
        for (int rr = 0; rr < 4; rr++) {
            const int t = 16 * wv + 4 * q4 + rr;
            const int s = 16 * sn + l15;
            scb[t][s] = __float2bfloat16((s <= t) ? sc4[sn][rr] : 0.f);
        }
    }
    __syncthreads();   // scb ready

    // Fin = Sc·V : 64x32, K=64 (4 MFMAs/wave), stored in C-layout bf16
    f32x4 fin[2] = {(f32x4){0.f,0.f,0.f,0.f}, (f32x4){0.f,0.f,0.f,0.f}};
#pragma unroll
    for (int kb = 0; kb < 2; kb++) {
        short8 ap8 = *(const short8*)(&scb[16 * wv + l15][kb * 32 + q4 * 8]);
#pragma unroll
        for (int rn = 0; rn < 2; rn++) {
            short8 bv8 = *(const short8*)(&vT[16 * rn + l15][kb * 32 + q4 * 8]);
            fin[rn] = __builtin_amdgcn_mfma_f32_16x16x32_bf16(ap8, bv8, fin[rn], 0, 0, 0);
        }
    }
    {
        bf8pack pf;
#pragma unroll
        for (int rr = 0; rr < 4; rr++) {
            pf.h[rr]     = __float2bfloat16(fin[0][rr]);
            pf.h[4 + rr] = __float2bfloat16(fin[1][rr]);
        }
        *(short8*)(Fin + ((size_t)(ch * 4 + wv) * 64 + lane) * 8) = pf.v;
    }
}

// ---------------------------------------------------------------------------
// K2 (B1, slim): per-superchunk totals only (Wtotal, Atot). 64 blocks,
// 16 iters; Wlocal/AP are recomputed locally by phaseC instead.
// ---------------------------------------------------------------------------
__global__ __launch_bounds__(256) void phaseB1_kernel(
    const float* __restrict__ Schunk, const float* __restrict__ Pchunk,
    float* __restrict__ Wtotal, float* __restrict__ Atot)
{
    const int sc  = blockIdx.x;
    const int tid = threadIdx.x;
    const int e4  = tid * 4;
    float4 w = make_float4(0.f, 0.f, 0.f, 0.f);
    float  a = 1.f;
#pragma unroll 4
    for (int c = 0; c < SCH; c++) {
        const int ch = sc * SCH + c;
        const float p = Pchunk[ch];
        float4 s = *(const float4*)(Schunk + (size_t)ch * 1024 + e4);
        w.x = p * w.x + s.x;  w.y = p * w.y + s.y;
        w.z = p * w.z + s.z;  w.w = p * w.w + s.w;
        a *= p;
    }
    *(float4*)(Wtotal + (size_t)sc * 1024 + e4) = w;
    if (tid == 0) Atot[sc] = a;
}

// ---------------------------------------------------------------------------
// K3 (phase C): local S-scan (<=15 iters) + inline-B2 (<=63 iters) +
// carried-state term + epilogue.
//   Wlocal/ap: scan sibling S tiles (L2/L3-hot, loop-invariant addresses)
//   Wsuper: scan Wtotal with Atot
//   fast = Fin (C-layout, direct C-operand) + Q̃·Wst   [2 MFMAs]
//   out  = 1 + tanh(fast Wo^T + bo)                    [4 MFMAs + exp]
// ---------------------------------------------------------------------------
__global__ __launch_bounds__(256) void phaseC_kernel(
    const __hip_bfloat16* __restrict__ Qtil,
    const __hip_bfloat16* __restrict__ Fin,
    const float* __restrict__ Schunk, const float* __restrict__ Pchunk,
    const float* __restrict__ Wtotal, const float* __restrict__ Atot,
    const __hip_bfloat16* __restrict__ WoFrag, const float* __restrict__ bo,
    float* __restrict__ out)
{
    __shared__ __hip_bfloat16 WstT[32][40];     // Wst^T, bf16
    __shared__ __hip_bfloat16 fastB[CHUNK][40]; // fast_out, bf16 (A-frag for epi)
    __shared__ float bosS[MDIM];

    const int tid  = threadIdx.x;
    const int wv   = tid >> 6;
    const int lane = tid & 63;
    const int l15  = lane & 15;
    const int q4   = lane >> 4;
    const int ch   = blockIdx.x;
    const int t0   = ch * CHUNK;
    const int scid = ch / SCH;

    // local scan: Wlocal[ch] and ap = prod P over [sc start, ch)
    {
        const int e4  = tid * 4;
        const int sc0 = scid * SCH;
        float4 w = make_float4(0.f, 0.f, 0.f, 0.f);
        float ap = 1.f;
        for (int c = sc0; c < ch; c++) {
            const float p = Pchunk[c];
            float4 s = *(const float4*)(Schunk + (size_t)c * 1024 + e4);
            w.x = p * w.x + s.x;  w.y = p * w.y + s.y;
            w.z = p * w.z + s.z;  w.w = p * w.w + s.w;
            ap *= p;
        }
        // inline B2: Wsuper[scid]
        float4 wu = make_float4(0.f, 0.f, 0.f, 0.f);
        for (int s = 0; s < scid; s++) {
            const float p = Atot[s];
            float4 t = *(const float4*)(Wtotal + (size_t)s * 1024 + e4);
            wu.x = p * wu.x + t.x;  wu.y = p * wu.y + t.y;
            wu.z = p * wu.z + t.z;  wu.w = p * wu.w + t.w;
        }
        const int a  = tid >> 3;
        const int r0 = (tid & 7) * 4;
        WstT[r0 + 0][a] = __float2bfloat16(ap * wu.x + w.x);
        WstT[r0 + 1][a] = __float2bfloat16(ap * wu.y + w.y);
        WstT[r0 + 2][a] = __float2bfloat16(ap * wu.z + w.z);
        WstT[r0 + 3][a] = __float2bfloat16(ap * wu.w + w.w);
    }
    if (tid < MDIM) bosS[tid] = bo[tid];

    // A-fragment: q̃ rows of this wave's t-tile
    const short8 aq = *(const short8*)(Qtil + (size_t)(t0 + 16 * wv + l15) * 32 + q4 * 8);
    // Fin (C-layout) -> C-operand init
    bf8pack pf;
    pf.v = *(const short8*)(Fin + ((size_t)(ch * 4 + wv) * 64 + lane) * 8);
    f32x4 fa[2];
#pragma unroll
    for (int rr = 0; rr < 4; rr++) {
        fa[0][rr] = __bfloat162float(pf.h[rr]);
        fa[1][rr] = __bfloat162float(pf.h[4 + rr]);
    }
    __syncthreads();   // WstT ready

    // fast = Fin + Q̃·Wst
#pragma unroll
    for (int rn = 0; rn < 2; rn++) {
        short8 bw8 = *(const short8*)(&WstT[16 * rn + l15][q4 * 8]);
        fa[rn] = __builtin_amdgcn_mfma_f32_16x16x32_bf16(aq, bw8, fa[rn], 0, 0, 0);
    }
    // fast -> LDS (bf16, A-frag layout source)
#pragma unroll
    for (int rn = 0; rn < 2; rn++)
#pragma unroll
        for (int rr = 0; rr < 4; rr++)
            fastB[16 * wv + 4 * q4 + rr][16 * rn + l15] = __float2bfloat16(fa[rn][rr]);
    __syncthreads();

    // epilogue: out = 1 + tanh(fast @ Wo^T + bo), via 4 MFMAs/wave (K=32)
    {
        const short8 aF = *(const short8*)(&fastB[16 * wv + l15][q4 * 8]);
#pragma unroll
        for (int c = 0; c < 4; c++) {
            short8 bF = *(const short8*)(WoFrag + ((size_t)(c * 64) + lane) * 8);
            f32x4 oc = __builtin_amdgcn_mfma_f32_16x16x32_bf16(
                aF, bF, (f32x4){0.f, 0.f, 0.f, 0.f}, 0, 0, 0);
            const int mm = 16 * c + l15;
            if (mm < MDIM) {
                const float bb = bosS[mm];
#pragma unroll
                for (int rr = 0; rr < 4; rr++) {
                    const int t = 16 * wv + 4 * q4 + rr;
                    out[(size_t)(t0 + t) * MDIM + mm] =
                        2.0f / (1.0f + __expf(-2.0f * (oc[rr] + bb)));
                }
            }
        }
    }
}

// ---------------------------------------------------------------------------
extern "C" void kernel_launch(void* const* d_in, const int* in_sizes, int n_in,
                              void* d_out, int out_size, void* d_ws, size_t ws_size,
                              hipStream_t stream) {
    (void)in_sizes; (void)n_in; (void)out_size; (void)ws_size;
    const float* X   = (const float*)d_in[0];
    const float* lr  = (const float*)d_in[1];
    const float* dec = (const float*)d_in[2];
    const float* Wk  = (const float*)d_in[3];
    const float* bk  = (const float*)d_in[4];
    const float* Wv  = (const float*)d_in[5];
    const float* bv  = (const float*)d_in[6];
    const float* Wq  = (const float*)d_in[7];
    const float* bq  = (const float*)d_in[8];
    const float* Wo  = (const float*)d_in[9];
    const float* bo  = (const float*)d_in[10];
    float* out = (float*)d_out;

    // workspace (floats unless noted):
    // S[NCH*1024] | P[NCH] | Wtotal[NSC*1024] | Atot[NSC]
    // | Qtil(bf16 T*32) | Fin(bf16 T*32) | Bfrag | WoFrag
    float* ws    = (float*)d_ws;
    float* S     = ws;
    float* P     = S + (size_t)NCH * 1024;
    float* Wtot  = P + NCH;
    float* Atot  = Wtot + (size_t)NSC * 1024;
    __hip_bfloat16* Qtil   = (__hip_bfloat16*)(Atot + NSC);
    __hip_bfloat16* Fin    = Qtil + (size_t)T_STEPS * 32;
    __hip_bfloat16* Bfrag  = Fin + (size_t)T_STEPS * 32;
    __hip_bfloat16* WoFrag = Bfrag + (size_t)96 * 256;

    prepB_kernel<<<13, 256, 0, stream>>>(Wk, Wv, Wq, Wo, Bfrag, WoFrag);
    projA_kernel<<<NCH, 256, 0, stream>>>(X, lr, dec, bk, bv, bq, Bfrag,
                                          Qtil, Fin, S, P);
    phaseB1_kernel<<<NSC, 256, 0, stream>>>(S, P, Wtot, Atot);
    phaseC_kernel<<<NCH, 256, 0, stream>>>(Qtil, Fin, S, P,
                                           Wtot, Atot, WoFrag, bo, out);
}